// Round 20
// baseline (2306.394 us; speedup 1.0000x reference)
//
#include <hip/hip_runtime.h>
#include <math.h>

#define B_TOT 512
#define T_FR  18
#define NSTEP 16

typedef __attribute__((ext_vector_type(8))) short bf16x8;
typedef __attribute__((ext_vector_type(4))) float f32x4;

__device__ __forceinline__ float gelu_f(float x) {
    return 0.5f * x * (1.0f + erff(x * 0.70710678118654752f));
}
__device__ __forceinline__ float sigmoid_f(float x) {
    return 1.0f / (1.0f + expf(-x));
}
__device__ __forceinline__ short f2bf(float x) {
    unsigned int u = __float_as_uint(x);
    return (short)((u + 0x7FFFu + ((u >> 16) & 1u)) >> 16);
}
__device__ __forceinline__ float bflo(unsigned int u) { return __uint_as_float(u << 16); }
__device__ __forceinline__ float bfhi(unsigned int u) { return __uint_as_float(u & 0xffff0000u); }
__device__ __forceinline__ float bf2f(short s) {
    return __uint_as_float(((unsigned int)(unsigned short)s) << 16);
}
__device__ __forceinline__ bf16x8 ld_bf8(const short* p) {
    const short4 lo = *reinterpret_cast<const short4*>(p);
    const short4 hi = *reinterpret_cast<const short4*>(p + 4);
    bf16x8 r;
    r[0] = lo.x; r[1] = lo.y; r[2] = lo.z; r[3] = lo.w;
    r[4] = hi.x; r[5] = hi.y; r[6] = hi.z; r[7] = hi.w;
    return r;
}

#define MFMA(a, bb, c) __builtin_amdgcn_mfma_f32_16x16x32_bf16((a), (bb), (c), 0, 0, 0)

// ---------------------------------------------------------------- init ----
__global__ __launch_bounds__(256) void init_kernel(
    const float* __restrict__ mask_w, const float* __restrict__ mask_b,
    const float* __restrict__ e2w,
    const float* __restrict__ wih, const float* __restrict__ whh,
    const float* __restrict__ qw,
    const float* __restrict__ tsw, const float* __restrict__ tsb,
    const float* __restrict__ kw, const float* __restrict__ vw,
    const float* __restrict__ e1w, const float* __restrict__ e1b,
    float* __restrict__ rmw, float* __restrict__ rmb,
    float* __restrict__ kbf, float* __restrict__ vbf,
    short* __restrict__ w2bf, short* __restrict__ wihbf, short* __restrict__ whhbf,
    short* __restrict__ qwbf, short* __restrict__ kwf, short* __restrict__ vwf,
    short* __restrict__ e1wbf)
{
    const int tid = threadIdx.x, bid = blockIdx.x;
    const int gid = bid * 256 + tid, gstr = gridDim.x * 256;
    const float rscale = 0.08838834764831845f;  // 1/sqrt(128)

    for (int i = gid; i < 128 * 2048; i += gstr) w2bf[i] = f2bf(e2w[i]);
    for (int i = gid; i < 384 * 128; i += gstr) {
        wihbf[i] = f2bf(wih[i]);
        whhbf[i] = f2bf(whh[i]);
    }
    for (int i = gid; i < 128 * 128; i += gstr) qwbf[i] = f2bf(qw[i] * rscale);
    for (int i = gid; i < 128 * 32; i += gstr) {
        const int ci = i >> 5, k = i & 31;
        float v = 0.f;
        if (k < 18) v = e1w[ci * 18 + k];
        else if (k == 18) v = e1b[ci];
        e1wbf[i] = f2bf(v);
    }

    if (bid < 128) {
        const int j = bid;
        if (tid < 128) {
            float s = 0.f;
            for (int d = 0; d < 128; ++d) s += kw[j * 128 + d] * tsw[d * 128 + tid];
            kwf[j * 128 + tid] = f2bf(s);
        } else if (tid == 128) {
            float s = 0.f;
            for (int d = 0; d < 128; ++d) s += kw[j * 128 + d] * tsb[d];
            kbf[j] = s;
        }
    } else if (bid < 256) {
        const int j = bid - 128;
        if (tid < 128) {
            float s = 0.f;
            for (int d = 0; d < 128; ++d) s += vw[j * 128 + d] * tsw[d * 128 + tid];
            vwf[j * 128 + tid] = f2bf(s);
        } else if (tid == 128) {
            float s = 0.f;
            for (int d = 0; d < 128; ++d) s += vw[j * 128 + d] * tsb[d];
            vbf[j] = s;
        }
    }
    if (bid == 256) {
        for (int i = tid; i < 2048; i += 256) {
            const int j = i >> 7, d = i & 127;
            float s = 0.f;
            for (int c = 0; c < 128; ++c) s += mask_w[(c * 16 + j) * 128 + d];
            rmw[i] = s * (1.0f / 128.0f);
        }
        for (int i = tid; i < 16; i += 256) {
            float s = 0.f;
            for (int c = 0; c < 128; ++c) s += mask_b[c * 16 + i];
            rmb[i] = s * (1.0f / 128.0f);
        }
    }
}

// ------------------------------------- parallel encoder pre-pass ----------
#define E_PAIR 0      // 2048
#define E_F1S  2048   // 20480
#define E_F2T  22528  // 4224
#define E_E2B  26752  // 512
#define E_KBF  27264  // 512
#define E_VBF  27776  // 512 -> 28288
#define EPOOLSZ 28288

__global__ __launch_bounds__(256, 2) void encoder_all_kernel(
    const float* __restrict__ frames,
    const short* __restrict__ w2bf, const short* __restrict__ e1wbf,
    const float* __restrict__ e2b_g,
    const short* __restrict__ kwf, const short* __restrict__ vwf,
    const float* __restrict__ kbf_g, const float* __restrict__ vbf_g,
    short* __restrict__ kk_g, short* __restrict__ vv_g)
{
    __shared__ __align__(16) char POOL[EPOOLSZ];
    float* PAIR = (float*)(POOL + E_PAIR);
    short* F1S  = (short*)(POOL + E_F1S);
    short* F2T  = (short*)(POOL + E_F2T);
    float* E2B  = (float*)(POOL + E_E2B);
    float* KBF  = (float*)(POOL + E_KBF);
    float* VBF  = (float*)(POOL + E_VBF);

    const int tid = threadIdx.x;
    const int lane = tid & 63, w = tid >> 6;
    const int g = lane >> 4, cn = lane & 15;
    const int bid = blockIdx.x;
    const int b = bid >> 4, t = bid & 15;
    const int arow = (2 * w) * 16 + cn;
    const int bcol = (4 * (cn >> 2) + (g & 1) * 2) * 20 + 4 * (cn & 3);

    PAIR[tid]       = frames[((size_t)b * T_FR + t + 1) * 256 + tid];
    PAIR[256 + tid] = frames[((size_t)b * T_FR + t) * 256 + tid];
    if (tid < 128) {
        E2B[tid] = e2b_g[tid];
        KBF[tid] = kbf_g[tid];
        VBF[tid] = vbf_g[tid];
    }
    __syncthreads();

    bf16x8 bimj[4];
#pragma unroll
    for (int j = 0; j < 4; ++j) {
        const int pyp = 4 * w + j;
#pragma unroll
        for (int k = 0; k < 8; ++k) {
            const int K = g * 8 + k;
            short v;
            if (K < 18) {
                const int chn = (K >= 9) ? 1 : 0;
                const int q = K - 9 * chn;
                const int ky = q / 3, kx = q - 3 * ky;
                const int yy = pyp + ky - 1, xx = cn + kx - 1;
                const bool ok = (yy >= 0 && yy < 16 && xx >= 0 && xx < 16);
                v = ok ? f2bf(PAIR[chn * 256 + yy * 16 + xx]) : (short)0;
            } else if (K == 18) {
                v = (short)0x3F80;
            } else {
                v = 0;
            }
            bimj[j][k] = v;
        }
    }

    f32x4 acc0 = {0.f, 0.f, 0.f, 0.f};
    f32x4 acc1 = {0.f, 0.f, 0.f, 0.f};
    for (int ch = 0; ch < 4; ++ch) {
        {
            const bf16x8 aw0 = *(const bf16x8*)&e1wbf[(size_t)(ch * 32 + cn) * 32 + g * 8];
            const bf16x8 aw1 = *(const bf16x8*)&e1wbf[(size_t)(ch * 32 + 16 + cn) * 32 + g * 8];
            f32x4 c0[4], c1[4];
#pragma unroll
            for (int j = 0; j < 4; ++j) {
                c0[j] = (f32x4){0.f, 0.f, 0.f, 0.f};
                c1[j] = (f32x4){0.f, 0.f, 0.f, 0.f};
            }
#pragma unroll
            for (int j = 0; j < 4; ++j) {
                c0[j] = MFMA(aw0, bimj[j], c0[j]);
                c1[j] = MFMA(aw1, bimj[j], c1[j]);
            }
#pragma unroll
            for (int j = 0; j < 4; ++j)
#pragma unroll
            for (int r = 0; r < 4; ++r) {
                F1S[(4 * g + r) * 320 + (4 * w + j) * 20 + cn] = f2bf(gelu_f(c0[j][r]));
                F1S[(16 + 4 * g + r) * 320 + (4 * w + j) * 20 + cn] = f2bf(gelu_f(c1[j][r]));
            }
        }
        __syncthreads();
        int rb = (g >> 1) * 320 + bcol;
        int k0 = ch * 512 + g * 8;
        for (int kt = 0; kt < 16; ++kt) {
            const short4 lo = *(const short4*)&F1S[rb];
            const short4 hi = *(const short4*)&F1S[rb + 20];
            bf16x8 bfr;
            bfr[0] = lo.x; bfr[1] = lo.y; bfr[2] = lo.z; bfr[3] = lo.w;
            bfr[4] = hi.x; bfr[5] = hi.y; bfr[6] = hi.z; bfr[7] = hi.w;
            const bf16x8 a0 = *(const bf16x8*)&w2bf[(size_t)arow * 2048 + k0];
            const bf16x8 a1 = *(const bf16x8*)&w2bf[(size_t)(arow + 16) * 2048 + k0];
            acc0 = MFMA(a0, bfr, acc0);
            acc1 = MFMA(a1, bfr, acc1);
            rb += 640; k0 += 32;
        }
        __syncthreads();
    }
    {
        const int cob0 = (2 * w) * 16 + g * 4;
        short4 s0, s1;
        s0.x = f2bf(gelu_f(acc0[0] + E2B[cob0]));
        s0.y = f2bf(gelu_f(acc0[1] + E2B[cob0 + 1]));
        s0.z = f2bf(gelu_f(acc0[2] + E2B[cob0 + 2]));
        s0.w = f2bf(gelu_f(acc0[3] + E2B[cob0 + 3]));
        s1.x = f2bf(gelu_f(acc1[0] + E2B[cob0 + 16]));
        s1.y = f2bf(gelu_f(acc1[1] + E2B[cob0 + 17]));
        s1.z = f2bf(gelu_f(acc1[2] + E2B[cob0 + 18]));
        s1.w = f2bf(gelu_f(acc1[3] + E2B[cob0 + 19]));
        *(short4*)&F2T[cn * 132 + cob0] = s0;
        *(short4*)&F2T[cn * 132 + cob0 + 16] = s1;
    }
    __syncthreads();

    {
        bf16x8 aT[4];
#pragma unroll
        for (int kt = 0; kt < 4; ++kt)
            aT[kt] = ld_bf8(&F2T[cn * 132 + kt * 32 + g * 8]);
        const short* wf = (w >> 1) ? vwf : kwf;
        const int h2 = w & 1;
        f32x4 ac[4];
#pragma unroll
        for (int nt = 0; nt < 4; ++nt) ac[nt] = (f32x4){0.f, 0.f, 0.f, 0.f};
#pragma unroll
        for (int kt = 0; kt < 4; ++kt)
#pragma unroll
        for (int nt = 0; nt < 4; ++nt)
            ac[nt] = MFMA(aT[kt],
                *(const bf16x8*)&wf[(size_t)(h2 * 64 + nt * 16 + cn) * 128 + kt * 32 + g * 8],
                ac[nt]);
        short* dst = (w >> 1) ? vv_g : kk_g;
        const float* bias = (w >> 1) ? VBF : KBF;
        const size_t base = (size_t)bid * 2048;
#pragma unroll
        for (int nt = 0; nt < 4; ++nt) {
            const int j = h2 * 64 + nt * 16 + cn;
            const float bb = bias[j];
#pragma unroll
            for (int r = 0; r < 4; ++r)
                dst[base + (4 * g + r) * 128 + j] = f2bf(ac[nt][r] + bb);
        }
    }
}

// --------------------------------- sequential attention+GRU kernel --------
// wave-redundant attention: 1 barrier per iteration (4 barriers/step)
#define PO_BIH   0      // 1536
#define PO_BHH   1536   // 1536
#define PO_SLOTS 3072   // 4096
#define PO_SLB0  7168   // 4224
#define PO_SLB1  11392  // 4224 -> 15616
#define T_KK     15616  // 4224
#define T_VV     19840  // 4224 -> 24064
#define T_QQW    24064  // 4 x 4224 = 16896 -> 40960
#define T_UPDW   40960  // 16896 -> 57856
#define T_ATTW   57856  // 4 x 512 = 2048 -> 59904
#define POOLSZ2  59904

#define LDW(mat, row, kt) (*(const bf16x8*)&mat[(size_t)(row) * 128 + (kt) * 32 + g * 8])

__global__ __launch_bounds__(256, 2) void fused_seq_kernel(
    const float* __restrict__ slot_mu,
    short* __restrict__ kk_g, const short* __restrict__ vv_g,
    const short* __restrict__ qwbf,
    const short* __restrict__ wihbf, const short* __restrict__ whhbf,
    const float* __restrict__ bih_g, const float* __restrict__ bhh_g)
{
    __shared__ __align__(16) char POOL[POOLSZ2];
    const int tid = threadIdx.x;
    const int lane = tid & 63, w = tid >> 6;
    const int g = lane >> 4, cn = lane & 15;
    const int b = blockIdx.x;

    float* BIH = (float*)(POOL + PO_BIH);
    float* BHH = (float*)(POOL + PO_BHH);
    float* SLOTS = (float*)(POOL + PO_SLOTS);
    short* SLB0 = (short*)(POOL + PO_SLB0);
    short* SLB1 = (short*)(POOL + PO_SLB1);
    short* KKl  = (short*)(POOL + T_KK);
    short* VVl  = (short*)(POOL + T_VV);
    short* QQW  = (short*)(POOL + T_QQW) + w * 2112;   // wave-private [16][132]
    short* UPDW = (short*)(POOL + T_UPDW) + w * 2112;  // wave-private [16][132]
    float* ATTW = (float*)(POOL + T_ATTW) + w * 128;   // wave-private [8][16]

    for (int i = tid; i < 384; i += 256) { BIH[i] = bih_g[i]; BHH[i] = bhh_g[i]; }
    for (int i = tid; i < 1024; i += 256) {
        const float v = slot_mu[i];
        SLOTS[i] = v;
        SLB0[(i >> 7) * 132 + (i & 127)] = f2bf(v);
    }
    for (int i = tid; i < 8 * 132; i += 256) {
        SLB0[8 * 132 + i] = 0;
        SLB1[8 * 132 + i] = 0;
    }

    const int col0 = 32 * w;
    int cur = 0;
    __syncthreads();

#pragma unroll 1
    for (int t = 0; t < NSTEP; ++t) {
        // kk/vv load (coalesced 16B per thread per buffer)
        {
            const size_t base = ((size_t)b * 16 + t) * 2048;
            const int row = tid >> 4, c8 = (tid & 15) * 8;
            const short4 klo = *(const short4*)&kk_g[base + row * 128 + c8];
            const short4 khi = *(const short4*)&kk_g[base + row * 128 + c8 + 4];
            const short4 vlo = *(const short4*)&vv_g[base + row * 128 + c8];
            const short4 vhi = *(const short4*)&vv_g[base + row * 128 + c8 + 4];
            *(short4*)&KKl[row * 132 + c8] = klo;
            *(short4*)&KKl[row * 132 + c8 + 4] = khi;
            *(short4*)&VVl[row * 132 + c8] = vlo;
            *(short4*)&VVl[row * 132 + c8 + 4] = vhi;
        }
        __syncthreads();

        for (int it = 0; it < 3; ++it) {
            short* SLBr = cur ? SLB1 : SLB0;
            short* SLBw = cur ? SLB0 : SLB1;
            bf16x8 aS[4];
#pragma unroll
            for (int kt = 0; kt < 4; ++kt)
                aS[kt] = ld_bf8(&SLBr[cn * 132 + kt * 32 + g * 8]);
            // qq: FULL 8 col-tiles per wave -> wave-private QQW
#pragma unroll
            for (int nt = 0; nt < 8; ++nt) {
                f32x4 qa = {0.f, 0.f, 0.f, 0.f};
#pragma unroll
                for (int kt = 0; kt < 4; ++kt)
                    qa = MFMA(aS[kt], LDW(qwbf, nt * 16 + cn, kt), qa);
#pragma unroll
                for (int r = 0; r < 4; ++r)
                    QQW[(4 * g + r) * 132 + nt * 16 + cn] = f2bf(qa[r]);
            }
            // logits: A = QQW rows, B = KK rows (same-wave LDS RAW, no barrier)
            {
                bf16x8 aQ[4];
#pragma unroll
                for (int kt = 0; kt < 4; ++kt)
                    aQ[kt] = ld_bf8(&QQW[cn * 132 + kt * 32 + g * 8]);
                f32x4 lg = {0.f, 0.f, 0.f, 0.f};
#pragma unroll
                for (int kt = 0; kt < 4; ++kt) {
                    const bf16x8 bK = ld_bf8(&KKl[cn * 132 + kt * 32 + g * 8]);
                    lg = MFMA(aQ[kt], bK, lg);
                }
                // softmax over kq in-wave (rows 0-7 live in g=0,1 lanes)
                float m = fmaxf(fmaxf(lg[0], lg[1]), fmaxf(lg[2], lg[3]));
                m = fmaxf(m, __shfl_xor(m, 16));
                float e0 = expf(lg[0] - m), e1 = expf(lg[1] - m);
                float e2 = expf(lg[2] - m), e3 = expf(lg[3] - m);
                float s = e0 + e1 + e2 + e3;
                s += __shfl_xor(s, 16);
                const float inv = 1.f / s;
                if (g < 2) {
                    ATTW[(4 * g + 0) * 16 + cn] = e0 * inv;
                    ATTW[(4 * g + 1) * 16 + cn] = e1 * inv;
                    ATTW[(4 * g + 2) * 16 + cn] = e2 * inv;
                    ATTW[(4 * g + 3) * 16 + cn] = e3 * inv;
                }
            }
            // upd per-lane: lane -> (kq = lane>>3, d-slice = (lane&7)*16)
            {
                const int kq = lane >> 3, d0 = (lane & 7) * 16;
                float acc[16];
#pragma unroll
                for (int q = 0; q < 16; ++q) acc[q] = 0.f;
#pragma unroll
                for (int n = 0; n < 16; ++n) {
                    const float at = ATTW[kq * 16 + n];
                    const short* vr = &VVl[n * 132 + d0];
#pragma unroll
                    for (int q = 0; q < 4; ++q) {
                        const uint2 v2 = *(const uint2*)&vr[q * 4];
                        acc[q * 4 + 0] += at * bflo(v2.x);
                        acc[q * 4 + 1] += at * bfhi(v2.x);
                        acc[q * 4 + 2] += at * bflo(v2.y);
                        acc[q * 4 + 3] += at * bfhi(v2.y);
                    }
                }
#pragma unroll
                for (int q = 0; q < 4; ++q) {
                    short4 sv;
                    sv.x = f2bf(acc[q * 4 + 0]); sv.y = f2bf(acc[q * 4 + 1]);
                    sv.z = f2bf(acc[q * 4 + 2]); sv.w = f2bf(acc[q * 4 + 3]);
                    *(short4*)&UPDW[kq * 132 + d0 + q * 4] = sv;
                }
            }
            // GRU for this wave's 32 columns
            {
                bf16x8 aU[4];
#pragma unroll
                for (int kt = 0; kt < 4; ++kt)
                    aU[kt] = ld_bf8(&UPDW[cn * 132 + kt * 32 + g * 8]);
                f32x4 aR[2], aZ[2], aNIv[2], aNHv[2];
#pragma unroll
                for (int nt = 0; nt < 2; ++nt) {
                    aR[nt] = (f32x4){0.f, 0.f, 0.f, 0.f};
                    aZ[nt] = (f32x4){0.f, 0.f, 0.f, 0.f};
                    aNIv[nt] = (f32x4){0.f, 0.f, 0.f, 0.f};
                    aNHv[nt] = (f32x4){0.f, 0.f, 0.f, 0.f};
                }
#pragma unroll
                for (int nt = 0; nt < 2; ++nt) {
                    const int colj = col0 + nt * 16 + cn;
#pragma unroll
                    for (int kt = 0; kt < 4; ++kt) {
                        aR[nt]   = MFMA(aU[kt], LDW(wihbf, colj, kt), aR[nt]);
                        aR[nt]   = MFMA(aS[kt], LDW(whhbf, colj, kt), aR[nt]);
                        aZ[nt]   = MFMA(aU[kt], LDW(wihbf, 128 + colj, kt), aZ[nt]);
                        aZ[nt]   = MFMA(aS[kt], LDW(whhbf, 128 + colj, kt), aZ[nt]);
                        aNIv[nt] = MFMA(aU[kt], LDW(wihbf, 256 + colj, kt), aNIv[nt]);
                        aNHv[nt] = MFMA(aS[kt], LDW(whhbf, 256 + colj, kt), aNHv[nt]);
                    }
                }
                if (g < 2) {
#pragma unroll
                    for (int nt = 0; nt < 2; ++nt) {
                        const int colj = col0 + nt * 16 + cn;
                        const float br = BIH[colj] + BHH[colj];
                        const float bz = BIH[128 + colj] + BHH[128 + colj];
                        const float bi = BIH[256 + colj], bh = BHH[256 + colj];
#pragma unroll
                        for (int r = 0; r < 4; ++r) {
                            const int kq = 4 * g + r;
                            const float rr = sigmoid_f(aR[nt][r] + br);
                            const float zz = sigmoid_f(aZ[nt][r] + bz);
                            const float nn = tanhf(aNIv[nt][r] + bi + rr * (aNHv[nt][r] + bh));
                            const float hold = SLOTS[kq * 128 + colj];
                            const float hv = (1.f - zz) * nn + zz * hold;
                            SLOTS[kq * 128 + colj] = hv;
                            SLBw[kq * 132 + colj] = f2bf(hv);
                        }
                    }
                }
                __syncthreads();   // ONLY barrier in the iteration
            }
            cur ^= 1;
        }

        // store this step's slot state into dead kk region
        {
            short* SLBr = cur ? SLB1 : SLB0;
            const size_t base = ((size_t)b * 16 + t) * 2048;
            const int i4 = tid * 4;
            const int row = i4 >> 7, col = i4 & 127;
            *(short4*)&kk_g[base + i4] = *(const short4*)&SLBr[row * 132 + col];
        }
    }
}

// ---------------------------------- parallel decode kernel ----------------
#define D_SLB  0       // 2112
#define D_M1W  2112    // 8448
#define D_RMW  10560   // 4224
#define D_UPW  14784   // 4096
#define D_R1W  18880   // 2304
#define D_R2W  21184   // 2304
#define D_M1B  23488   // 128
#define D_M2W  23616   // 256
#define D_M2B  23872   // 16
#define D_UPB  23888   // 32
#define D_RMB  23920   // 64
#define D_R2B  23984   // 16
#define D_R1B  24000   // 256
#define D_IMG  24256   // 1024
#define D_MASK 25280   // 8192
#define D_WARP 33472   // 1024
#define D_DIFF 34496   // 1024
#define D_M1O  35520   // 1024
#define D_MOT  36544   // 128
#define D_MLL  36672   // 512
#define D_R1S  37184   // 8448 -> 45632
#define POOLSZ3 45632

__global__ __launch_bounds__(256, 2) void decode_all_kernel(
    const float* __restrict__ frames,
    const short* __restrict__ slots_g,
    const float* __restrict__ m1w_g, const float* __restrict__ m1b_g,
    const float* __restrict__ m2w_g, const float* __restrict__ m2b_g,
    const float* __restrict__ upw_g, const float* __restrict__ upb_g,
    const float* __restrict__ r1w_g, const float* __restrict__ r1b_g,
    const float* __restrict__ r2w_g, const float* __restrict__ r2b_g,
    const float* __restrict__ rmw_g, const float* __restrict__ rmb_g,
    float* __restrict__ out)
{
    __shared__ __align__(16) char POOL[POOLSZ3];
    short* SLB = (short*)(POOL + D_SLB);
    short* M1W = (short*)(POOL + D_M1W);
    short* RMW = (short*)(POOL + D_RMW);
    float* UPW = (float*)(POOL + D_UPW);
    float* R1W = (float*)(POOL + D_R1W);
    float* R2W = (float*)(POOL + D_R2W);
    float* M1B = (float*)(POOL + D_M1B);
    float* M2W = (float*)(POOL + D_M2W);
    float* M2B = (float*)(POOL + D_M2B);
    float* UPB = (float*)(POOL + D_UPB);
    float* RMB = (float*)(POOL + D_RMB);
    float* R2B = (float*)(POOL + D_R2B);
    float* R1B = (float*)(POOL + D_R1B);
    float* IMG = (float*)(POOL + D_IMG);
    float* MASKl = (float*)(POOL + D_MASK);
    float* WARP = (float*)(POOL + D_WARP);
    float* DIFF = (float*)(POOL + D_DIFF);
    float* M1O  = (float*)(POOL + D_M1O);
    float* MOT  = (float*)(POOL + D_MOT);
    float* MLL  = (float*)(POOL + D_MLL);
    short* R1S  = (short*)(POOL + D_R1S);

    const int tid = threadIdx.x;
    const int bid = blockIdx.x;
    const int b = bid >> 4, t = bid & 15;
    const int py = tid >> 4, pxx = tid & 15;

    {
        const size_t base = (size_t)bid * 2048;
        const int i4 = tid * 4;
        const int row = i4 >> 7, col = i4 & 127;
        *(short4*)&SLB[row * 132 + col] = *(const short4*)&slots_g[base + i4];
    }
    for (int i = tid; i < 4096; i += 256)
        M1W[(i >> 7) * 132 + (i & 127)] = f2bf(m1w_g[i]);
    for (int i = tid; i < 2048; i += 256)
        RMW[(i >> 7) * 132 + (i & 127)] = f2bf(rmw_g[i]);
    for (int i = tid; i < 1024; i += 256) UPW[i] = upw_g[i];
    for (int i = tid; i < 576; i += 256) { R1W[i] = r1w_g[i]; R2W[i] = r2w_g[i]; }
    if (tid < 32) M1B[tid] = m1b_g[tid];
    if (tid < 64) { M2W[tid] = m2w_g[tid]; R1B[tid] = r1b_g[tid]; }
    if (tid < 2) M2B[tid] = m2b_g[tid];
    if (tid < 8) UPB[tid] = upb_g[tid];
    if (tid < 16) RMB[tid] = rmb_g[tid];
    if (tid == 0) R2B[0] = r2b_g[0];
    IMG[tid] = frames[((size_t)b * T_FR + t + 1) * 256 + tid];
    __syncthreads();

    {
        const int kq = tid >> 5, c = tid & 31;
        float a = M1B[c];
        for (int d = 0; d < 128; d += 4) {
            const uint2 s2 = *(const uint2*)&SLB[kq * 132 + d];
            const uint2 w2 = *(const uint2*)&M1W[c * 132 + d];
            a += bflo(s2.x) * bflo(w2.x) + bfhi(s2.x) * bfhi(w2.x)
               + bflo(s2.y) * bflo(w2.y) + bfhi(s2.y) * bfhi(w2.y);
        }
        M1O[kq * 32 + c] = gelu_f(a);
    }
    if (tid < 128) {
        const int kq = tid >> 4, j = tid & 15;
        float a = RMB[j];
        for (int d = 0; d < 128; d += 4) {
            const uint2 s2 = *(const uint2*)&SLB[kq * 132 + d];
            const uint2 w2 = *(const uint2*)&RMW[j * 132 + d];
            a += bflo(s2.x) * bflo(w2.x) + bfhi(s2.x) * bfhi(w2.x)
               + bflo(s2.y) * bflo(w2.y) + bfhi(s2.y) * bfhi(w2.y);
        }
        MLL[kq * 16 + j] = a;
    }
    __syncthreads();
    if (tid < 16) {
        const int kq = tid >> 1, e = tid & 1;
        float a = M2B[e];
#pragma unroll
        for (int c = 0; c < 32; ++c) a += M1O[kq * 32 + c] * M2W[e * 32 + c];
        MOT[kq * 2 + e] = tanhf(a) * 4.0f;
    }
    {
        const int jj = (py >> 2) * 4 + (pxx >> 2);
        const int wq = (py & 3) * 4 + (pxx & 3);
#pragma unroll
        for (int ko = 0; ko < 8; ++ko) {
            float a = UPB[ko];
#pragma unroll
            for (int i8 = 0; i8 < 8; ++i8)
                a += MLL[i8 * 16 + jj] * UPW[(i8 * 8 + ko) * 16 + wq];
            MASKl[ko * 256 + tid] = a;
        }
    }
    __syncthreads();
    {
        float m = -1e30f;
#pragma unroll
        for (int kq = 0; kq < 8; ++kq) m = fmaxf(m, MASKl[kq * 256 + tid]);
        float e[8], ssum = 0.f;
#pragma unroll
        for (int kq = 0; kq < 8; ++kq) { e[kq] = expf(MASKl[kq * 256 + tid] - m); ssum += e[kq]; }
        const float inv = 1.f / ssum;
        const float gxv = -1.0f + (2.0f / 15.0f) * pxx;
        const float gyv = -1.0f + (2.0f / 15.0f) * py;
        float wsum = 0.f;
#pragma unroll
        for (int kq = 0; kq < 8; ++kq) {
            const float fx = MOT[kq * 2 + 0] * 0.125f;
            const float fy = MOT[kq * 2 + 1] * 0.125f;
            const float sgx = fminf(fmaxf(gxv + fx, -1.f), 1.f);
            const float sgy = fminf(fmaxf(gyv + fy, -1.f), 1.f);
            const float ix = (sgx + 1.f) * 7.5f;
            const float iy = (sgy + 1.f) * 7.5f;
            const float x0f = floorf(ix), y0f = floorf(iy);
            const float wx = ix - x0f, wy = iy - y0f;
            const int x0 = (int)x0f, y0 = (int)y0f;
            const int x1 = min(x0 + 1, 15), y1 = min(y0 + 1, 15);
            const float v00 = IMG[y0 * 16 + x0], v01 = IMG[y0 * 16 + x1];
            const float v10 = IMG[y1 * 16 + x0], v11 = IMG[y1 * 16 + x1];
            const float val = (1.f - wy) * ((1.f - wx) * v00 + wx * v01) +
                              wy * ((1.f - wx) * v10 + wx * v11);
            wsum += (e[kq] * inv) * val;
        }
        WARP[tid] = wsum;
        DIFF[tid] = wsum - IMG[tid];
    }
    __syncthreads();
    float nbz[9];
#pragma unroll
    for (int ky = 0; ky < 3; ++ky)
#pragma unroll
    for (int kx = 0; kx < 3; ++kx) {
        const int y2 = py + ky - 1, x2 = pxx + kx - 1;
        const bool ok = (y2 >= 0 && y2 < 16 && x2 >= 0 && x2 < 16);
        nbz[ky * 3 + kx] = ok ? DIFF[y2 * 16 + x2] : 0.f;
    }
    float racc = 0.f;
    for (int c0 = 0; c0 < 64; c0 += 16) {
#pragma unroll 4
        for (int cl = 0; cl < 16; ++cl) {
            const int c = c0 + cl;
            float a = R1B[c];
#pragma unroll
            for (int q = 0; q < 9; ++q) a += nbz[q] * R1W[c * 9 + q];
            R1S[cl * 264 + tid] = f2bf(gelu_f(a));
        }
        __syncthreads();
#pragma unroll 4
        for (int cl = 0; cl < 16; ++cl) {
            const float* r2r = &R2W[(c0 + cl) * 9];
#pragma unroll
            for (int ky = 0; ky < 3; ++ky)
#pragma unroll
            for (int kx = 0; kx < 3; ++kx) {
                const int y2 = py + ky - 1, x2 = pxx + kx - 1;
                if (y2 >= 0 && y2 < 16 && x2 >= 0 && x2 < 16)
                    racc += bf2f(R1S[cl * 264 + y2 * 16 + x2]) * r2r[ky * 3 + kx];
            }
        }
        __syncthreads();
    }
    const float resv = tanhf(racc + R2B[0]) * 0.1f;
    const float pred = fminf(fmaxf(WARP[tid] + resv, 0.f), 1.f);
    out[((size_t)b * NSTEP + t) * 256 + tid] = pred;
}

// -------------------------------------------------------------- launch ----
extern "C" void kernel_launch(void* const* d_in, const int* in_sizes, int n_in,
                              void* d_out, int out_size, void* d_ws, size_t ws_size,
                              hipStream_t stream)
{
    const float* frames = (const float*)d_in[0];
    const float* e1w = (const float*)d_in[1];
    const float* e1b = (const float*)d_in[2];
    const float* e2w = (const float*)d_in[3];
    const float* e2b = (const float*)d_in[4];
    const float* slot_mu = (const float*)d_in[5];
    const float* tsw = (const float*)d_in[6];
    const float* tsb = (const float*)d_in[7];
    const float* qw = (const float*)d_in[8];
    const float* kw = (const float*)d_in[9];
    const float* vw = (const float*)d_in[10];
    const float* wih = (const float*)d_in[11];
    const float* whh = (const float*)d_in[12];
    const float* bih = (const float*)d_in[13];
    const float* bhh = (const float*)d_in[14];
    const float* m1w = (const float*)d_in[15];
    const float* m1b = (const float*)d_in[16];
    const float* m2w = (const float*)d_in[17];
    const float* m2b = (const float*)d_in[18];
    const float* maskw = (const float*)d_in[19];
    const float* maskb = (const float*)d_in[20];
    const float* upw = (const float*)d_in[21];
    const float* upb = (const float*)d_in[22];
    const float* r1w = (const float*)d_in[23];
    const float* r1b = (const float*)d_in[24];
    const float* r2w = (const float*)d_in[25];
    const float* r2b = (const float*)d_in[26];

    float* ws = (float*)d_ws;
    float* rmw  = ws + 0;
    float* rmb  = ws + 2048;
    float* kbf  = ws + 2064;
    float* vbf  = ws + 2192;
    short* w2bf  = (short*)(ws + 2320);
    short* wihbf = (short*)(ws + 133392);
    short* whhbf = (short*)(ws + 157968);
    short* qwbf  = (short*)(ws + 182544);
    short* kwf   = (short*)(ws + 190736);
    short* vwf   = (short*)(ws + 198928);
    short* e1wbf = (short*)(ws + 207120);
    short* kk_g  = (short*)(ws + 209168);
    short* vv_g  = (short*)(ws + 209168 + 8388608);

    hipLaunchKernelGGL(init_kernel, dim3(512), dim3(256), 0, stream,
                       maskw, maskb, e2w, wih, whh, qw, tsw, tsb, kw, vw,
                       e1w, e1b,
                       rmw, rmb, kbf, vbf, w2bf, wihbf, whhbf, qwbf, kwf, vwf,
                       e1wbf);
    hipLaunchKernelGGL(encoder_all_kernel, dim3(B_TOT * NSTEP), dim3(256), 0, stream,
                       frames, w2bf, e1wbf, e2b, kwf, vwf, kbf, vbf, kk_g, vv_g);
    hipLaunchKernelGGL(fused_seq_kernel, dim3(B_TOT), dim3(256), 0, stream,
                       slot_mu, kk_g, vv_g, qwbf, wihbf, whhbf, bih, bhh);
    hipLaunchKernelGGL(decode_all_kernel, dim3(B_TOT * NSTEP), dim3(256), 0, stream,
                       frames, kk_g, m1w, m1b, m2w, m2b, upw, upb,
                       r1w, r1b, r2w, r2b, rmw, rmb,
                       (float*)d_out);
}

// Round 21
// 1557.489 us; speedup vs baseline: 1.4808x; 1.4808x over previous
//
#include <hip/hip_runtime.h>
#include <math.h>

#define B_TOT 512
#define T_FR  18
#define NSTEP 16

typedef __attribute__((ext_vector_type(8))) short bf16x8;
typedef __attribute__((ext_vector_type(4))) float f32x4;

__device__ __forceinline__ float gelu_f(float x) {
    return 0.5f * x * (1.0f + erff(x * 0.70710678118654752f));
}
__device__ __forceinline__ float sigmoid_f(float x) {
    return 1.0f / (1.0f + expf(-x));
}
__device__ __forceinline__ short f2bf(float x) {
    unsigned int u = __float_as_uint(x);
    return (short)((u + 0x7FFFu + ((u >> 16) & 1u)) >> 16);
}
__device__ __forceinline__ float bflo(unsigned int u) { return __uint_as_float(u << 16); }
__device__ __forceinline__ float bfhi(unsigned int u) { return __uint_as_float(u & 0xffff0000u); }
__device__ __forceinline__ float bf2f(short s) {
    return __uint_as_float(((unsigned int)(unsigned short)s) << 16);
}
__device__ __forceinline__ bf16x8 ld_bf8(const short* p) {
    const short4 lo = *reinterpret_cast<const short4*>(p);
    const short4 hi = *reinterpret_cast<const short4*>(p + 4);
    bf16x8 r;
    r[0] = lo.x; r[1] = lo.y; r[2] = lo.z; r[3] = lo.w;
    r[4] = hi.x; r[5] = hi.y; r[6] = hi.z; r[7] = hi.w;
    return r;
}

#define MFMA(a, bb, c) __builtin_amdgcn_mfma_f32_16x16x32_bf16((a), (bb), (c), 0, 0, 0)

// ---------------------------------------------------------------- init ----
__global__ __launch_bounds__(256) void init_kernel(
    const float* __restrict__ mask_w, const float* __restrict__ mask_b,
    const float* __restrict__ e2w,
    const float* __restrict__ wih, const float* __restrict__ whh,
    const float* __restrict__ qw,
    const float* __restrict__ tsw, const float* __restrict__ tsb,
    const float* __restrict__ kw, const float* __restrict__ vw,
    const float* __restrict__ e1w, const float* __restrict__ e1b,
    float* __restrict__ rmw, float* __restrict__ rmb,
    float* __restrict__ kbf, float* __restrict__ vbf,
    short* __restrict__ w2bf, short* __restrict__ wihbf, short* __restrict__ whhbf,
    short* __restrict__ qwbf, short* __restrict__ kwf, short* __restrict__ vwf,
    short* __restrict__ e1wbf)
{
    const int tid = threadIdx.x, bid = blockIdx.x;
    const int gid = bid * 256 + tid, gstr = gridDim.x * 256;
    const float rscale = 0.08838834764831845f;  // 1/sqrt(128)

    for (int i = gid; i < 128 * 2048; i += gstr) w2bf[i] = f2bf(e2w[i]);
    for (int i = gid; i < 384 * 128; i += gstr) {
        wihbf[i] = f2bf(wih[i]);
        whhbf[i] = f2bf(whh[i]);
    }
    for (int i = gid; i < 128 * 128; i += gstr) qwbf[i] = f2bf(qw[i] * rscale);
    for (int i = gid; i < 128 * 32; i += gstr) {
        const int ci = i >> 5, k = i & 31;
        float v = 0.f;
        if (k < 18) v = e1w[ci * 18 + k];
        else if (k == 18) v = e1b[ci];
        e1wbf[i] = f2bf(v);
    }

    if (bid < 128) {
        const int j = bid;
        if (tid < 128) {
            float s = 0.f;
            for (int d = 0; d < 128; ++d) s += kw[j * 128 + d] * tsw[d * 128 + tid];
            kwf[j * 128 + tid] = f2bf(s);
        } else if (tid == 128) {
            float s = 0.f;
            for (int d = 0; d < 128; ++d) s += kw[j * 128 + d] * tsb[d];
            kbf[j] = s;
        }
    } else if (bid < 256) {
        const int j = bid - 128;
        if (tid < 128) {
            float s = 0.f;
            for (int d = 0; d < 128; ++d) s += vw[j * 128 + d] * tsw[d * 128 + tid];
            vwf[j * 128 + tid] = f2bf(s);
        } else if (tid == 128) {
            float s = 0.f;
            for (int d = 0; d < 128; ++d) s += vw[j * 128 + d] * tsb[d];
            vbf[j] = s;
        }
    }
    if (bid == 256) {
        for (int i = tid; i < 2048; i += 256) {
            const int j = i >> 7, d = i & 127;
            float s = 0.f;
            for (int c = 0; c < 128; ++c) s += mask_w[(c * 16 + j) * 128 + d];
            rmw[i] = s * (1.0f / 128.0f);
        }
        for (int i = tid; i < 16; i += 256) {
            float s = 0.f;
            for (int c = 0; c < 128; ++c) s += mask_b[c * 16 + i];
            rmb[i] = s * (1.0f / 128.0f);
        }
    }
}

// ------------------------------------- parallel encoder pre-pass ----------
// grid = 8192 blocks (b*16 + t), 256 threads; writes kk/vv bf16 to global.
#define E_PAIR 0      // 2048
#define E_IM2C 2048   // 18432
#define E_F1S  20480  // 20480
#define E_F2T  40960  // 4224
#define E_E2B  45184  // 512
#define E_KBF  45696  // 512
#define E_VBF  46208  // 512 -> 46720
#define EPOOLSZ 46720

__global__ __launch_bounds__(256, 2) void encoder_all_kernel(
    const float* __restrict__ frames,
    const short* __restrict__ w2bf, const short* __restrict__ e1wbf,
    const float* __restrict__ e2b_g,
    const short* __restrict__ kwf, const short* __restrict__ vwf,
    const float* __restrict__ kbf_g, const float* __restrict__ vbf_g,
    short* __restrict__ kk_g, short* __restrict__ vv_g)
{
    __shared__ __align__(16) char POOL[EPOOLSZ];
    float* PAIR = (float*)(POOL + E_PAIR);
    short* IM2C = (short*)(POOL + E_IM2C);
    short* F1S  = (short*)(POOL + E_F1S);
    short* F2T  = (short*)(POOL + E_F2T);
    float* E2B  = (float*)(POOL + E_E2B);
    float* KBF  = (float*)(POOL + E_KBF);
    float* VBF  = (float*)(POOL + E_VBF);

    const int tid = threadIdx.x;
    const int lane = tid & 63, w = tid >> 6;
    const int g = lane >> 4, cn = lane & 15;
    const int bid = blockIdx.x;
    const int b = bid >> 4, t = bid & 15;
    const int py = tid >> 4, pxx = tid & 15;
    const int arow = (2 * w) * 16 + cn;
    const int bcol = (4 * (cn >> 2) + (g & 1) * 2) * 20 + 4 * (cn & 3);

    PAIR[tid]       = frames[((size_t)b * T_FR + t + 1) * 256 + tid];
    PAIR[256 + tid] = frames[((size_t)b * T_FR + t) * 256 + tid];
    if (tid < 128) {
        E2B[tid] = e2b_g[tid];
        KBF[tid] = kbf_g[tid];
        VBF[tid] = vbf_g[tid];
    }
    __syncthreads();

    // im2col [pos][36]
    {
        short* imr = &IM2C[tid * 36];
#pragma unroll
        for (int ky = 0; ky < 3; ++ky)
#pragma unroll
        for (int kx = 0; kx < 3; ++kx) {
            const int yy = py + ky - 1, xx = pxx + kx - 1;
            const bool ok = (yy >= 0 && yy < 16 && xx >= 0 && xx < 16);
            const int q = ky * 3 + kx;
            imr[q]     = ok ? f2bf(PAIR[yy * 16 + xx]) : (short)0;
            imr[9 + q] = ok ? f2bf(PAIR[256 + yy * 16 + xx]) : (short)0;
        }
        imr[18] = (short)0x3F80;
        imr[19] = 0;
        short4 z4; z4.x = 0; z4.y = 0; z4.z = 0; z4.w = 0;
        *(short4*)&imr[20] = z4;
        *(short4*)&imr[24] = z4;
        *(short4*)&imr[28] = z4;
    }
    __syncthreads();

    f32x4 acc0 = {0.f, 0.f, 0.f, 0.f};
    f32x4 acc1 = {0.f, 0.f, 0.f, 0.f};
    for (int ch = 0; ch < 4; ++ch) {
        {
            const bf16x8 aw0 = *(const bf16x8*)&e1wbf[(size_t)(ch * 32 + cn) * 32 + g * 8];
            const bf16x8 aw1 = *(const bf16x8*)&e1wbf[(size_t)(ch * 32 + 16 + cn) * 32 + g * 8];
            f32x4 c0[4], c1[4];
#pragma unroll
            for (int j = 0; j < 4; ++j) {
                c0[j] = (f32x4){0.f, 0.f, 0.f, 0.f};
                c1[j] = (f32x4){0.f, 0.f, 0.f, 0.f};
            }
#pragma unroll
            for (int j = 0; j < 4; ++j) {
                const int pos = (4 * w + j) * 16 + cn;
                const bf16x8 bim = ld_bf8(&IM2C[pos * 36 + g * 8]);
                c0[j] = MFMA(aw0, bim, c0[j]);
                c1[j] = MFMA(aw1, bim, c1[j]);
            }
#pragma unroll
            for (int j = 0; j < 4; ++j)
#pragma unroll
            for (int r = 0; r < 4; ++r) {
                F1S[(4 * g + r) * 320 + (4 * w + j) * 20 + cn] = f2bf(gelu_f(c0[j][r]));
                F1S[(16 + 4 * g + r) * 320 + (4 * w + j) * 20 + cn] = f2bf(gelu_f(c1[j][r]));
            }
        }
        __syncthreads();
        int rb = (g >> 1) * 320 + bcol;
        int k0 = ch * 512 + g * 8;
        for (int kt = 0; kt < 16; ++kt) {
            const short4 lo = *(const short4*)&F1S[rb];
            const short4 hi = *(const short4*)&F1S[rb + 20];
            bf16x8 bfr;
            bfr[0] = lo.x; bfr[1] = lo.y; bfr[2] = lo.z; bfr[3] = lo.w;
            bfr[4] = hi.x; bfr[5] = hi.y; bfr[6] = hi.z; bfr[7] = hi.w;
            const bf16x8 a0 = *(const bf16x8*)&w2bf[(size_t)arow * 2048 + k0];
            const bf16x8 a1 = *(const bf16x8*)&w2bf[(size_t)(arow + 16) * 2048 + k0];
            acc0 = MFMA(a0, bfr, acc0);
            acc1 = MFMA(a1, bfr, acc1);
            rb += 640; k0 += 32;
        }
        __syncthreads();
    }
    {
        const int cob0 = (2 * w) * 16 + g * 4;
        short4 s0, s1;
        s0.x = f2bf(gelu_f(acc0[0] + E2B[cob0]));
        s0.y = f2bf(gelu_f(acc0[1] + E2B[cob0 + 1]));
        s0.z = f2bf(gelu_f(acc0[2] + E2B[cob0 + 2]));
        s0.w = f2bf(gelu_f(acc0[3] + E2B[cob0 + 3]));
        s1.x = f2bf(gelu_f(acc1[0] + E2B[cob0 + 16]));
        s1.y = f2bf(gelu_f(acc1[1] + E2B[cob0 + 17]));
        s1.z = f2bf(gelu_f(acc1[2] + E2B[cob0 + 18]));
        s1.w = f2bf(gelu_f(acc1[3] + E2B[cob0 + 19]));
        *(short4*)&F2T[cn * 132 + cob0] = s0;
        *(short4*)&F2T[cn * 132 + cob0 + 16] = s1;
    }
    __syncthreads();

    // kk/vv -> global bf16
    {
        bf16x8 aT[4];
#pragma unroll
        for (int kt = 0; kt < 4; ++kt)
            aT[kt] = ld_bf8(&F2T[cn * 132 + kt * 32 + g * 8]);
        const short* wf = (w >> 1) ? vwf : kwf;
        const int h2 = w & 1;
        f32x4 ac[4];
#pragma unroll
        for (int nt = 0; nt < 4; ++nt) ac[nt] = (f32x4){0.f, 0.f, 0.f, 0.f};
#pragma unroll
        for (int kt = 0; kt < 4; ++kt)
#pragma unroll
        for (int nt = 0; nt < 4; ++nt)
            ac[nt] = MFMA(aT[kt],
                *(const bf16x8*)&wf[(size_t)(h2 * 64 + nt * 16 + cn) * 128 + kt * 32 + g * 8],
                ac[nt]);
        short* dst = (w >> 1) ? vv_g : kk_g;
        const float* bias = (w >> 1) ? VBF : KBF;
        const size_t base = (size_t)bid * 2048;
#pragma unroll
        for (int nt = 0; nt < 4; ++nt) {
            const int j = h2 * 64 + nt * 16 + cn;
            const float bb = bias[j];
#pragma unroll
            for (int r = 0; r < 4; ++r)
                dst[base + (4 * g + r) * 128 + j] = f2bf(ac[nt][r] + bb);
        }
    }
}

// --------------------------------- sequential attention+GRU kernel --------
#define PO_BIH   0      // 1536
#define PO_BHH   1536   // 1536
#define PO_SLOTS 3072   // 4096
#define PO_SLB   7168   // 4224 -> 11392
#define SCR2     11392
#define T_KK   0
#define T_VV   4224
#define T_QQ   8448
#define T_UPD  12672
#define T_ATT  16896    // 512 -> 17408
#define POOLSZ2 (11392 + 17408)

#define LDW(mat, row, kt) (*(const bf16x8*)&mat[(size_t)(row) * 128 + (kt) * 32 + g * 8])

__global__ __launch_bounds__(256, 2) void fused_seq_kernel(
    const float* __restrict__ slot_mu,
    short* __restrict__ kk_g, const short* __restrict__ vv_g,
    const short* __restrict__ qwbf,
    const short* __restrict__ wihbf, const short* __restrict__ whhbf,
    const float* __restrict__ bih_g, const float* __restrict__ bhh_g)
{
    __shared__ __align__(16) char POOL[POOLSZ2];
    const int tid = threadIdx.x;
    const int lane = tid & 63, w = tid >> 6;
    const int g = lane >> 4, cn = lane & 15;
    const int b = blockIdx.x;

    float* BIH = (float*)(POOL + PO_BIH);
    float* BHH = (float*)(POOL + PO_BHH);
    float* SLOTS = (float*)(POOL + PO_SLOTS);
    short* SLB = (short*)(POOL + PO_SLB);

    short* KKl  = (short*)(POOL + SCR2 + T_KK);
    short* VVl  = (short*)(POOL + SCR2 + T_VV);
    short* QQB  = (short*)(POOL + SCR2 + T_QQ);
    short* UPDB = (short*)(POOL + SCR2 + T_UPD);
    float* ATT  = (float*)(POOL + SCR2 + T_ATT);

    for (int i = tid; i < 384; i += 256) { BIH[i] = bih_g[i]; BHH[i] = bhh_g[i]; }
    for (int i = tid; i < 1024; i += 256) {
        const float v = slot_mu[i];
        SLOTS[i] = v;
        SLB[(i >> 7) * 132 + (i & 127)] = f2bf(v);
    }
    for (int i = tid; i < 8 * 132; i += 256) SLB[8 * 132 + i] = 0;

    const int col0 = 32 * w;
    __syncthreads();

#pragma unroll 1
    for (int t = 0; t < NSTEP; ++t) {
        // kk/vv load (coalesced 16B per thread per buffer)
        {
            const size_t base = ((size_t)b * 16 + t) * 2048;
            const int row = tid >> 4, c8 = (tid & 15) * 8;
            const short4 klo = *(const short4*)&kk_g[base + row * 128 + c8];
            const short4 khi = *(const short4*)&kk_g[base + row * 128 + c8 + 4];
            const short4 vlo = *(const short4*)&vv_g[base + row * 128 + c8];
            const short4 vhi = *(const short4*)&vv_g[base + row * 128 + c8 + 4];
            *(short4*)&KKl[row * 132 + c8] = klo;
            *(short4*)&KKl[row * 132 + c8 + 4] = khi;
            *(short4*)&VVl[row * 132 + c8] = vlo;
            *(short4*)&VVl[row * 132 + c8 + 4] = vhi;
        }
        __syncthreads();

        for (int it = 0; it < 3; ++it) {
            bf16x8 aS[4];
#pragma unroll
            for (int kt = 0; kt < 4; ++kt)
                aS[kt] = ld_bf8(&SLB[cn * 132 + kt * 32 + g * 8]);
            {
                f32x4 qa[2] = {{0.f, 0.f, 0.f, 0.f}, {0.f, 0.f, 0.f, 0.f}};
#pragma unroll
                for (int kt = 0; kt < 4; ++kt)
#pragma unroll
                for (int nt = 0; nt < 2; ++nt)
                    qa[nt] = MFMA(aS[kt], LDW(qwbf, col0 + nt * 16 + cn, kt), qa[nt]);
#pragma unroll
                for (int nt = 0; nt < 2; ++nt)
#pragma unroll
                for (int r = 0; r < 4; ++r)
                    QQB[(4 * g + r) * 132 + col0 + nt * 16 + cn] = f2bf(qa[nt][r]);
            }
            __syncthreads();
            if (tid < 128) {
                const int n = tid >> 3, k = tid & 7;
                float a = 0.f;
                for (int d = 0; d < 128; d += 4) {
                    const uint2 q2 = *(const uint2*)&QQB[k * 132 + d];
                    const uint2 k2 = *(const uint2*)&KKl[n * 132 + d];
                    a += bflo(q2.x) * bflo(k2.x) + bfhi(q2.x) * bfhi(k2.x)
                       + bflo(q2.y) * bflo(k2.y) + bfhi(q2.y) * bfhi(k2.y);
                }
                float m = a;
                m = fmaxf(m, __shfl_xor(m, 1));
                m = fmaxf(m, __shfl_xor(m, 2));
                m = fmaxf(m, __shfl_xor(m, 4));
                const float e = expf(a - m);
                float s = e;
                s += __shfl_xor(s, 1);
                s += __shfl_xor(s, 2);
                s += __shfl_xor(s, 4);
                ATT[k * 16 + n] = e / s;
            }
            __syncthreads();
            {
                const int k8 = tid >> 5, lg = tid & 31;
                float a0 = 0.f, a1 = 0.f, a2 = 0.f, a3 = 0.f;
#pragma unroll
                for (int n = 0; n < 16; ++n) {
                    const float at = ATT[k8 * 16 + n];
                    const uint2 v2 = *(const uint2*)&VVl[n * 132 + 4 * lg];
                    a0 += at * bflo(v2.x); a1 += at * bfhi(v2.x);
                    a2 += at * bflo(v2.y); a3 += at * bfhi(v2.y);
                }
                short4 sv;
                sv.x = f2bf(a0); sv.y = f2bf(a1); sv.z = f2bf(a2); sv.w = f2bf(a3);
                *(short4*)&UPDB[k8 * 132 + 4 * lg] = sv;
            }
            __syncthreads();
            {
                bf16x8 aU[4];
#pragma unroll
                for (int kt = 0; kt < 4; ++kt)
                    aU[kt] = ld_bf8(&UPDB[cn * 132 + kt * 32 + g * 8]);
                f32x4 aR[2], aZ[2], aNIv[2], aNHv[2];
#pragma unroll
                for (int nt = 0; nt < 2; ++nt) {
                    aR[nt] = (f32x4){0.f, 0.f, 0.f, 0.f};
                    aZ[nt] = (f32x4){0.f, 0.f, 0.f, 0.f};
                    aNIv[nt] = (f32x4){0.f, 0.f, 0.f, 0.f};
                    aNHv[nt] = (f32x4){0.f, 0.f, 0.f, 0.f};
                }
#pragma unroll
                for (int nt = 0; nt < 2; ++nt) {
                    const int colj = col0 + nt * 16 + cn;
#pragma unroll
                    for (int kt = 0; kt < 4; ++kt) {
                        aR[nt]   = MFMA(aU[kt], LDW(wihbf, colj, kt), aR[nt]);
                        aR[nt]   = MFMA(aS[kt], LDW(whhbf, colj, kt), aR[nt]);
                        aZ[nt]   = MFMA(aU[kt], LDW(wihbf, 128 + colj, kt), aZ[nt]);
                        aZ[nt]   = MFMA(aS[kt], LDW(whhbf, 128 + colj, kt), aZ[nt]);
                        aNIv[nt] = MFMA(aU[kt], LDW(wihbf, 256 + colj, kt), aNIv[nt]);
                        aNHv[nt] = MFMA(aS[kt], LDW(whhbf, 256 + colj, kt), aNHv[nt]);
                    }
                }
                __syncthreads();
                if (g < 2) {
#pragma unroll
                    for (int nt = 0; nt < 2; ++nt) {
                        const int colj = col0 + nt * 16 + cn;
                        const float br = BIH[colj] + BHH[colj];
                        const float bz = BIH[128 + colj] + BHH[128 + colj];
                        const float bi = BIH[256 + colj], bh = BHH[256 + colj];
#pragma unroll
                        for (int r = 0; r < 4; ++r) {
                            const int kq = 4 * g + r;
                            const float rr = sigmoid_f(aR[nt][r] + br);
                            const float zz = sigmoid_f(aZ[nt][r] + bz);
                            const float nn = tanhf(aNIv[nt][r] + bi + rr * (aNHv[nt][r] + bh));
                            const float hold = SLOTS[kq * 128 + colj];
                            const float hv = (1.f - zz) * nn + zz * hold;
                            SLOTS[kq * 128 + colj] = hv;
                            SLB[kq * 132 + colj] = f2bf(hv);
                        }
                    }
                }
                __syncthreads();
            }
        }

        // store this step's slot state into the (now dead) kk region
        {
            const size_t base = ((size_t)b * 16 + t) * 2048;
            const int i4 = tid * 4;
            const int row = i4 >> 7, col = i4 & 127;
            *(short4*)&kk_g[base + i4] = *(const short4*)&SLB[row * 132 + col];
        }
        __syncthreads();
    }
}

// ---------------------------------- parallel decode kernel ----------------
#define D_SLB  0       // 2112
#define D_M1W  2112    // 8448
#define D_RMW  10560   // 4224
#define D_UPW  14784   // 4096
#define D_R1W  18880   // 2304
#define D_R2W  21184   // 2304
#define D_M1B  23488   // 128
#define D_M2W  23616   // 256
#define D_M2B  23872   // 16
#define D_UPB  23888   // 32
#define D_RMB  23920   // 64
#define D_R2B  23984   // 16
#define D_R1B  24000   // 256
#define D_IMG  24256   // 1024
#define D_MASK 25280   // 8192
#define D_WARP 33472   // 1024
#define D_DIFF 34496   // 1024
#define D_M1O  35520   // 1024
#define D_MOT  36544   // 128
#define D_MLL  36672   // 512
#define D_R1S  37184   // 8448 -> 45632
#define POOLSZ3 45632

__global__ __launch_bounds__(256, 2) void decode_all_kernel(
    const float* __restrict__ frames,
    const short* __restrict__ slots_g,     // = kk_g (slot state per (b,t))
    const float* __restrict__ m1w_g, const float* __restrict__ m1b_g,
    const float* __restrict__ m2w_g, const float* __restrict__ m2b_g,
    const float* __restrict__ upw_g, const float* __restrict__ upb_g,
    const float* __restrict__ r1w_g, const float* __restrict__ r1b_g,
    const float* __restrict__ r2w_g, const float* __restrict__ r2b_g,
    const float* __restrict__ rmw_g, const float* __restrict__ rmb_g,
    float* __restrict__ out)
{
    __shared__ __align__(16) char POOL[POOLSZ3];
    short* SLB = (short*)(POOL + D_SLB);
    short* M1W = (short*)(POOL + D_M1W);
    short* RMW = (short*)(POOL + D_RMW);
    float* UPW = (float*)(POOL + D_UPW);
    float* R1W = (float*)(POOL + D_R1W);
    float* R2W = (float*)(POOL + D_R2W);
    float* M1B = (float*)(POOL + D_M1B);
    float* M2W = (float*)(POOL + D_M2W);
    float* M2B = (float*)(POOL + D_M2B);
    float* UPB = (float*)(POOL + D_UPB);
    float* RMB = (float*)(POOL + D_RMB);
    float* R2B = (float*)(POOL + D_R2B);
    float* R1B = (float*)(POOL + D_R1B);
    float* IMG = (float*)(POOL + D_IMG);
    float* MASKl = (float*)(POOL + D_MASK);
    float* WARP = (float*)(POOL + D_WARP);
    float* DIFF = (float*)(POOL + D_DIFF);
    float* M1O  = (float*)(POOL + D_M1O);
    float* MOT  = (float*)(POOL + D_MOT);
    float* MLL  = (float*)(POOL + D_MLL);
    short* R1S  = (short*)(POOL + D_R1S);

    const int tid = threadIdx.x;
    const int bid = blockIdx.x;
    const int b = bid >> 4, t = bid & 15;
    const int py = tid >> 4, pxx = tid & 15;

    // preload
    {
        const size_t base = (size_t)bid * 2048;
        const int i4 = tid * 4;
        const int row = i4 >> 7, col = i4 & 127;
        *(short4*)&SLB[row * 132 + col] = *(const short4*)&slots_g[base + i4];
    }
    for (int i = tid; i < 4096; i += 256)
        M1W[(i >> 7) * 132 + (i & 127)] = f2bf(m1w_g[i]);
    for (int i = tid; i < 2048; i += 256)
        RMW[(i >> 7) * 132 + (i & 127)] = f2bf(rmw_g[i]);
    for (int i = tid; i < 1024; i += 256) UPW[i] = upw_g[i];
    for (int i = tid; i < 576; i += 256) { R1W[i] = r1w_g[i]; R2W[i] = r2w_g[i]; }
    if (tid < 32) M1B[tid] = m1b_g[tid];
    if (tid < 64) { M2W[tid] = m2w_g[tid]; R1B[tid] = r1b_g[tid]; }
    if (tid < 2) M2B[tid] = m2b_g[tid];
    if (tid < 8) UPB[tid] = upb_g[tid];
    if (tid < 16) RMB[tid] = rmb_g[tid];
    if (tid == 0) R2B[0] = r2b_g[0];
    IMG[tid] = frames[((size_t)b * T_FR + t + 1) * 256 + tid];
    __syncthreads();

    {
        const int kq = tid >> 5, c = tid & 31;
        float a = M1B[c];
        for (int d = 0; d < 128; d += 4) {
            const uint2 s2 = *(const uint2*)&SLB[kq * 132 + d];
            const uint2 w2 = *(const uint2*)&M1W[c * 132 + d];
            a += bflo(s2.x) * bflo(w2.x) + bfhi(s2.x) * bfhi(w2.x)
               + bflo(s2.y) * bflo(w2.y) + bfhi(s2.y) * bfhi(w2.y);
        }
        M1O[kq * 32 + c] = gelu_f(a);
    }
    if (tid < 128) {
        const int kq = tid >> 4, j = tid & 15;
        float a = RMB[j];
        for (int d = 0; d < 128; d += 4) {
            const uint2 s2 = *(const uint2*)&SLB[kq * 132 + d];
            const uint2 w2 = *(const uint2*)&RMW[j * 132 + d];
            a += bflo(s2.x) * bflo(w2.x) + bfhi(s2.x) * bfhi(w2.x)
               + bflo(s2.y) * bflo(w2.y) + bfhi(s2.y) * bfhi(w2.y);
        }
        MLL[kq * 16 + j] = a;
    }
    __syncthreads();
    if (tid < 16) {
        const int kq = tid >> 1, e = tid & 1;
        float a = M2B[e];
#pragma unroll
        for (int c = 0; c < 32; ++c) a += M1O[kq * 32 + c] * M2W[e * 32 + c];
        MOT[kq * 2 + e] = tanhf(a) * 4.0f;
    }
    {
        const int jj = (py >> 2) * 4 + (pxx >> 2);
        const int wq = (py & 3) * 4 + (pxx & 3);
#pragma unroll
        for (int ko = 0; ko < 8; ++ko) {
            float a = UPB[ko];
#pragma unroll
            for (int i8 = 0; i8 < 8; ++i8)
                a += MLL[i8 * 16 + jj] * UPW[(i8 * 8 + ko) * 16 + wq];
            MASKl[ko * 256 + tid] = a;
        }
    }
    __syncthreads();
    {
        float m = -1e30f;
#pragma unroll
        for (int kq = 0; kq < 8; ++kq) m = fmaxf(m, MASKl[kq * 256 + tid]);
        float e[8], ssum = 0.f;
#pragma unroll
        for (int kq = 0; kq < 8; ++kq) { e[kq] = expf(MASKl[kq * 256 + tid] - m); ssum += e[kq]; }
        const float inv = 1.f / ssum;
        const float gxv = -1.0f + (2.0f / 15.0f) * pxx;
        const float gyv = -1.0f + (2.0f / 15.0f) * py;
        float wsum = 0.f;
#pragma unroll
        for (int kq = 0; kq < 8; ++kq) {
            const float fx = MOT[kq * 2 + 0] * 0.125f;
            const float fy = MOT[kq * 2 + 1] * 0.125f;
            const float sgx = fminf(fmaxf(gxv + fx, -1.f), 1.f);
            const float sgy = fminf(fmaxf(gyv + fy, -1.f), 1.f);
            const float ix = (sgx + 1.f) * 7.5f;
            const float iy = (sgy + 1.f) * 7.5f;
            const float x0f = floorf(ix), y0f = floorf(iy);
            const float wx = ix - x0f, wy = iy - y0f;
            const int x0 = (int)x0f, y0 = (int)y0f;
            const int x1 = min(x0 + 1, 15), y1 = min(y0 + 1, 15);
            const float v00 = IMG[y0 * 16 + x0], v01 = IMG[y0 * 16 + x1];
            const float v10 = IMG[y1 * 16 + x0], v11 = IMG[y1 * 16 + x1];
            const float val = (1.f - wy) * ((1.f - wx) * v00 + wx * v01) +
                              wy * ((1.f - wx) * v10 + wx * v11);
            wsum += (e[kq] * inv) * val;
        }
        WARP[tid] = wsum;
        DIFF[tid] = wsum - IMG[tid];
    }
    __syncthreads();
    float nbz[9];
#pragma unroll
    for (int ky = 0; ky < 3; ++ky)
#pragma unroll
    for (int kx = 0; kx < 3; ++kx) {
        const int y2 = py + ky - 1, x2 = pxx + kx - 1;
        const bool ok = (y2 >= 0 && y2 < 16 && x2 >= 0 && x2 < 16);
        nbz[ky * 3 + kx] = ok ? DIFF[y2 * 16 + x2] : 0.f;
    }
    float racc = 0.f;
    for (int c0 = 0; c0 < 64; c0 += 16) {
#pragma unroll 4
        for (int cl = 0; cl < 16; ++cl) {
            const int c = c0 + cl;
            float a = R1B[c];
#pragma unroll
            for (int q = 0; q < 9; ++q) a += nbz[q] * R1W[c * 9 + q];
            R1S[cl * 264 + tid] = f2bf(gelu_f(a));
        }
        __syncthreads();
#pragma unroll 4
        for (int cl = 0; cl < 16; ++cl) {
            const float* r2r = &R2W[(c0 + cl) * 9];
#pragma unroll
            for (int ky = 0; ky < 3; ++ky)
#pragma unroll
            for (int kx = 0; kx < 3; ++kx) {
                const int y2 = py + ky - 1, x2 = pxx + kx - 1;
                if (y2 >= 0 && y2 < 16 && x2 >= 0 && x2 < 16)
                    racc += bf2f(R1S[cl * 264 + y2 * 16 + x2]) * r2r[ky * 3 + kx];
            }
        }
        __syncthreads();
    }
    const float resv = tanhf(racc + R2B[0]) * 0.1f;
    const float pred = fminf(fmaxf(WARP[tid] + resv, 0.f), 1.f);
    out[((size_t)b * NSTEP + t) * 256 + tid] = pred;
}

// -------------------------------------------------------------- launch ----
extern "C" void kernel_launch(void* const* d_in, const int* in_sizes, int n_in,
                              void* d_out, int out_size, void* d_ws, size_t ws_size,
                              hipStream_t stream)
{
    const float* frames = (const float*)d_in[0];
    const float* e1w = (const float*)d_in[1];
    const float* e1b = (const float*)d_in[2];
    const float* e2w = (const float*)d_in[3];
    const float* e2b = (const float*)d_in[4];
    const float* slot_mu = (const float*)d_in[5];
    const float* tsw = (const float*)d_in[6];
    const float* tsb = (const float*)d_in[7];
    const float* qw = (const float*)d_in[8];
    const float* kw = (const float*)d_in[9];
    const float* vw = (const float*)d_in[10];
    const float* wih = (const float*)d_in[11];
    const float* whh = (const float*)d_in[12];
    const float* bih = (const float*)d_in[13];
    const float* bhh = (const float*)d_in[14];
    const float* m1w = (const float*)d_in[15];
    const float* m1b = (const float*)d_in[16];
    const float* m2w = (const float*)d_in[17];
    const float* m2b = (const float*)d_in[18];
    const float* maskw = (const float*)d_in[19];
    const float* maskb = (const float*)d_in[20];
    const float* upw = (const float*)d_in[21];
    const float* upb = (const float*)d_in[22];
    const float* r1w = (const float*)d_in[23];
    const float* r1b = (const float*)d_in[24];
    const float* r2w = (const float*)d_in[25];
    const float* r2b = (const float*)d_in[26];

    float* ws = (float*)d_ws;
    float* rmw  = ws + 0;                         // 2048
    float* rmb  = ws + 2048;                      // 16
    float* kbf  = ws + 2064;                      // 128
    float* vbf  = ws + 2192;                      // 128
    short* w2bf  = (short*)(ws + 2320);           // 131072 f
    short* wihbf = (short*)(ws + 133392);         // 24576 f
    short* whhbf = (short*)(ws + 157968);         // 24576 f
    short* qwbf  = (short*)(ws + 182544);         // 8192 f
    short* kwf   = (short*)(ws + 190736);         // 8192 f
    short* vwf   = (short*)(ws + 198928);         // 8192 f
    short* e1wbf = (short*)(ws + 207120);         // 2048 f
    short* kk_g  = (short*)(ws + 209168);         // 8388608 f
    short* vv_g  = (short*)(ws + 209168 + 8388608);

    hipLaunchKernelGGL(init_kernel, dim3(512), dim3(256), 0, stream,
                       maskw, maskb, e2w, wih, whh, qw, tsw, tsb, kw, vw,
                       e1w, e1b,
                       rmw, rmb, kbf, vbf, w2bf, wihbf, whhbf, qwbf, kwf, vwf,
                       e1wbf);
    hipLaunchKernelGGL(encoder_all_kernel, dim3(B_TOT * NSTEP), dim3(256), 0, stream,
                       frames, w2bf, e1wbf, e2b, kwf, vwf, kbf, vbf, kk_g, vv_g);
    hipLaunchKernelGGL(fused_seq_kernel, dim3(B_TOT), dim3(256), 0, stream,
                       slot_mu, kk_g, vv_g, qwbf, wihbf, whhbf, bih, bhh);
    hipLaunchKernelGGL(decode_all_kernel, dim3(B_TOT * NSTEP), dim3(256), 0, stream,
                       frames, kk_g, m1w, m1b, m2w, m2b, upw, upb,
                       r1w, r1b, r2w, r2b, rmw, rmb,
                       (float*)d_out);
}